// Round 5
// baseline (34.932 us; speedup 1.0000x reference)
//
#include <hip/hip_runtime.h>

#define NB 32
#define NP 32
#define NS 512
#define NPS (NP * NS)   // 16384
#define PHALF 16        // p's per block

typedef float f32x4 __attribute__((ext_vector_type(4)));

// ---------------------------------------------------------------------------
// Grid: (b, j-chunk of 1024, p-half) = 32*16*2 = 1024 blocks (4/CU, 16 waves/CU).
// Per block: 256 threads x 4 j. Phase 1: 32 threads build per-p params in LDS:
// rotation matrix R (forward; R^T = inverse/conjugate rotate), shape, trans,
// iou, vol*iou. Phase 2: each thread computes its 4 forward points once
// (p = R v + t, coef read once per p-half). Phase 3: loop 16 p's of this
// half: l = R^T (pt - t), pen, three coalesced float4 store streams.
// Rationale vs R4 (34.9us, 74% HBM): 2x blocks -> 16 waves/CU to keep store
// pipe fed through compute bubbles; matrix rotation cuts p-loop VALU ~30%.
// ---------------------------------------------------------------------------
__global__ void __launch_bounds__(256)
fused_all_p_kernel(const float* __restrict__ shape,   // (B,P,3)
                   const float* __restrict__ trans,   // (B,P,3)
                   const float* __restrict__ quat,    // (B,P,4)
                   const float* __restrict__ iou,     // (B,P)
                   const float* __restrict__ coef,    // (B,P,S,3)
                   float* __restrict__ out)           // tsdfOut | weight | tsdfGT
{
    const size_t TOT = (size_t)NB * NP * NPS;

    // per-p params: R[9], t[3], s[3], iou, vol*iou  -> 17 floats (pad 20)
    __shared__ float sP[NP][20];

    int blk   = blockIdx.x;
    int phalf = blk & 1;           // which half of the p loop
    int chunk = (blk >> 1) & 15;   // 16 chunks of 1024 j
    int b     = blk >> 5;
    int tid   = threadIdx.x;

    if (tid < NP) {
        int p  = tid;
        int bp = b * NP + p;
        const float* q = quat + (size_t)bp * 4;
        float qw = q[0], qx = q[1], qy = q[2], qz = q[3];
        float inv = 1.0f / sqrtf(qw*qw + qx*qx + qy*qy + qz*qz);
        qw *= inv; qx *= inv; qy *= inv; qz *= inv;
        // forward rotation matrix (row-major)
        sP[p][0] = 1.0f - 2.0f*(qy*qy + qz*qz);
        sP[p][1] = 2.0f*(qx*qy - qw*qz);
        sP[p][2] = 2.0f*(qx*qz + qw*qy);
        sP[p][3] = 2.0f*(qx*qy + qw*qz);
        sP[p][4] = 1.0f - 2.0f*(qx*qx + qz*qz);
        sP[p][5] = 2.0f*(qy*qz - qw*qx);
        sP[p][6] = 2.0f*(qx*qz - qw*qy);
        sP[p][7] = 2.0f*(qy*qz + qw*qx);
        sP[p][8] = 1.0f - 2.0f*(qx*qx + qy*qy);
        const float* tr = trans + (size_t)bp * 3;
        sP[p][9]  = tr[0]; sP[p][10] = tr[1]; sP[p][11] = tr[2];
        const float* sh = shape + (size_t)bp * 3;
        sP[p][12] = sh[0]; sP[p][13] = sh[1]; sP[p][14] = sh[2];
        float io = iou[bp];
        sP[p][15] = io;
        sP[p][16] = sh[0] * sh[1] * sh[2] * io;   // vol * iou
    }
    __syncthreads();

    int j0    = chunk * 1024 + tid * 4;
    int owner = j0 >> 9;            // constant for the thread's 4 j
    int js    = j0 & (NS - 1);

    // ---- owner (forward) params from LDS (broadcast / near-broadcast) ----
    float r00 = sP[owner][0], r01 = sP[owner][1], r02 = sP[owner][2];
    float r10 = sP[owner][3], r11 = sP[owner][4], r12 = sP[owner][5];
    float r20 = sP[owner][6], r21 = sP[owner][7], r22 = sP[owner][8];
    float otx = sP[owner][9], oty = sP[owner][10], otz = sP[owner][11];
    float osx = sP[owner][12], osy = sP[owner][13], osz = sP[owner][14];
    float wval = sP[owner][16];

    // ---- coef: 12 floats = 3 aligned float4 ----
    const f32x4* c4 = (const f32x4*)(coef + ((size_t)(b * NP + owner) * NS + js) * 3);
    f32x4 ca = c4[0], cb = c4[1], cc = c4[2];
    float cf[12] = {ca.x, ca.y, ca.z, ca.w,
                    cb.x, cb.y, cb.z, cb.w,
                    cc.x, cc.y, cc.z, cc.w};

    // ---- forward points, computed once, kept in registers ----
    float fx[4], fy[4], fz[4];
    #pragma unroll
    for (int k = 0; k < 4; ++k) {
        float vx = (2.0f * cf[3*k+0] - 1.0f) * osx;
        float vy = (2.0f * cf[3*k+1] - 1.0f) * osy;
        float vz = (2.0f * cf[3*k+2] - 1.0f) * osz;
        fx[k] = r00*vx + r01*vy + r02*vz + otx;
        fy[k] = r10*vx + r11*vy + r12*vz + oty;
        fz[k] = r20*vx + r21*vy + r22*vz + otz;
    }

    f32x4 wv = {wval, wval, wval, wval};
    f32x4 zv = {0.0f, 0.0f, 0.0f, 0.0f};

    int p0 = phalf * PHALF;
    size_t base = (size_t)(b * NP + p0) * NPS + j0;
    for (int p = p0; p < p0 + PHALF; ++p, base += NPS) {
        float m00 = sP[p][0], m01 = sP[p][1], m02 = sP[p][2];
        float m10 = sP[p][3], m11 = sP[p][4], m12 = sP[p][5];
        float m20 = sP[p][6], m21 = sP[p][7], m22 = sP[p][8];
        float tx  = sP[p][9], ty  = sP[p][10], tz = sP[p][11];
        float sx  = sP[p][12], sy = sP[p][13], sz = sP[p][14];
        float scale = sP[p][15] * ((owner != p) ? 1.0f : 0.0f);

        f32x4 res;
        #pragma unroll
        for (int k = 0; k < 4; ++k) {
            float rx = fx[k] - tx, ry = fy[k] - ty, rz = fz[k] - tz;
            // inverse rotate: R^T * r
            float lx = m00*rx + m10*ry + m20*rz;
            float ly = m01*rx + m11*ry + m21*rz;
            float lz = m02*rx + m12*ry + m22*rz;
            float px_ = fmaxf(sx - fabsf(lx), 0.0f);
            float py_ = fmaxf(sy - fabsf(ly), 0.0f);
            float pz_ = fmaxf(sz - fabsf(lz), 0.0f);
            res[k] = (px_*px_ + py_*py_ + pz_*pz_) * scale;
        }

        *(f32x4*)(out + base)           = res;
        *(f32x4*)(out + TOT + base)     = wv;
        *(f32x4*)(out + 2 * TOT + base) = zv;
    }
}

extern "C" void kernel_launch(void* const* d_in, const int* in_sizes, int n_in,
                              void* d_out, int out_size, void* d_ws, size_t ws_size,
                              hipStream_t stream) {
    const float* shape = (const float*)d_in[0];   // (B,P,3)
    const float* trans = (const float*)d_in[1];   // (B,P,3)
    const float* quat  = (const float*)d_in[2];   // (B,P,4)
    const float* iou   = (const float*)d_in[3];   // (B,P)
    const float* coef  = (const float*)d_in[4];   // (B,P,S,3)
    float* out = (float*)d_out;

    int nblocks = NB * 16 * 2;                    // 1024 blocks: (b, chunk, phalf)
    fused_all_p_kernel<<<nblocks, 256, 0, stream>>>(shape, trans, quat, iou, coef, out);
}